// Round 15
// baseline (108.429 us; speedup 1.0000x reference)
//
#include <hip/hip_runtime.h>
#include <hip/hip_cooperative_groups.h>
#include <math.h>

namespace cg = cooperative_groups;

#define TT 8192
#define DD 4096

typedef float  f32x4  __attribute__((ext_vector_type(4)));
typedef short  bf16x8 __attribute__((ext_vector_type(8)));
typedef unsigned int u32;

// ---------------- Fused cooperative kernel: split -> grid.sync -> GEMM -> grid.sync -> loss
// 256 blocks x 512 threads, 1 block/CU (co-resident). Phase work mappings and arithmetic
// chains are VERBATIM from the passing 3-kernel version (R11): bitwise-identical output.
__global__ __launch_bounds__(512, 4)
void gate_fused(const float* __restrict__ x, u32* __restrict__ wfrag,
                const float* __restrict__ noise, const float* __restrict__ gw2,
                float* __restrict__ out, float* __restrict__ part2,
                const float* __restrict__ gw1, const float* __restrict__ nw) {
  cg::grid_group grid = cg::this_grid();
  __shared__ float red[8][1024];     // 32 KB: [slice][e*32 + row_in_block]
  __shared__ float sg2[256];
  __shared__ float sred[8][32];      // loss phase
  const int t = threadIdx.x;
  const int bid = blockIdx.x;

  // ---------------- Phase A: split weights (blocks 0..31 reproduce split_w exactly) ------
  {
    const int tid = bid * 512 + t;
    if (tid < 16384) {
      const int s = tid >> 7;          // 0..127  (original blockIdx)
      const int tt = tid & 127;        // 0..127  (original threadIdx)
      const int h = tt >> 6, l = tt & 63;
      const int e = h * 16 + (l & 15);
      const float* src = ((e < 16) ? (gw1 + (size_t)e * DD) : (nw + (size_t)(e - 16) * DD))
                         + s * 32 + ((l >> 4) << 3);
      float f[8];
      *(float4*)&f[0] = *(const float4*)src;
      *(float4*)&f[4] = *(const float4*)(src + 4);
      u32 u0[8], u1[8], u2[8];
#pragma unroll
      for (int i = 0; i < 8; ++i) {
        u0[i] = __float_as_uint(f[i]);
        const float r1 = f[i] - __uint_as_float(u0[i] & 0xFFFF0000u);
        u1[i] = __float_as_uint(r1);
        const float r2 = r1 - __uint_as_float(u1[i] & 0xFFFF0000u);
        u2[i] = __float_as_uint(r2);
      }
      const size_t base = ((size_t)s * 2 + h) * 256 + l * 4;
#define PK(U) make_uint4((U[0]>>16)|(U[1]&0xFFFF0000u), (U[2]>>16)|(U[3]&0xFFFF0000u), \
                         (U[4]>>16)|(U[5]&0xFFFF0000u), (U[6]>>16)|(U[7]&0xFFFF0000u))
      *(uint4*)(wfrag + base)                 = PK(u0);
      *(uint4*)(wfrag + base + 128 * 512)     = PK(u1);
      *(uint4*)(wfrag + base + 2 * 128 * 512) = PK(u2);
#undef PK
    }
  }
  grid.sync();   // device-scope: wfrag visible to all XCDs

  // ---------------- Phase B: R11 GEMM body (verbatim; rt = bid) ----------------
  const int w = t >> 6, l = t & 63;
  const int rt = bid;                // 32-row tile 0..255
  if (t < 256) sg2[t] = gw2[t];

  const int r = l & 15, c = l >> 4;
  const float* xp0 = x + (size_t)(rt * 32 + r) * DD + w * 512 + (c << 3);
  const float* xp1 = xp0 + (size_t)16 * DD;
  const u32* wfl = wfrag + (size_t)l * 4 + (size_t)(w * 16) * 512;

  f32x4 g00 = {0,0,0,0}, g01 = g00, g02 = g00, n00 = g00, n01 = g00, n02 = g00;
  f32x4 g10 = g00, g11 = g00, g12 = g00, n10 = g00, n11 = g00, n12 = g00;

#define SPLIT8(FP, A0, A1, A2) \
  u32 pk_[12] __attribute__((aligned(16))); \
  { _Pragma("unroll") for (int p = 0; p < 4; ++p) { \
      const float fa = FP[2*p], fb = FP[2*p+1]; \
      const u32  a  = __float_as_uint(fa); \
      const float ra1 = fa - __uint_as_float(a & 0xFFFF0000u); \
      const u32  a1 = __float_as_uint(ra1); \
      const float ra2 = ra1 - __uint_as_float(a1 & 0xFFFF0000u); \
      const u32  a2 = __float_as_uint(ra2); \
      const u32  b  = __float_as_uint(fb); \
      const float rb1 = fb - __uint_as_float(b & 0xFFFF0000u); \
      const u32  b1 = __float_as_uint(rb1); \
      const float rb2 = rb1 - __uint_as_float(b1 & 0xFFFF0000u); \
      const u32  b2 = __float_as_uint(rb2); \
      pk_[p]     = (a  >> 16) | (b  & 0xFFFF0000u); \
      pk_[4 + p] = (a1 >> 16) | (b1 & 0xFFFF0000u); \
      pk_[8 + p] = (a2 >> 16) | (b2 & 0xFFFF0000u); } } \
  const bf16x8 A0 = *(const bf16x8*)&pk_[0]; \
  const bf16x8 A1 = *(const bf16x8*)&pk_[4]; \
  const bf16x8 A2 = *(const bf16x8*)&pk_[8];

#pragma unroll 2
  for (int sl = 0; sl < 16; ++sl) {
    const u32* wb = wfl + (size_t)sl * 512;
    const bf16x8 bg0 = *(const bf16x8*)(wb);
    const bf16x8 bn0 = *(const bf16x8*)(wb + 256);
    const bf16x8 bg1 = *(const bf16x8*)(wb + 128 * 512);
    const bf16x8 bn1 = *(const bf16x8*)(wb + 128 * 512 + 256);
    const bf16x8 bg2 = *(const bf16x8*)(wb + 2 * 128 * 512);
    const bf16x8 bn2 = *(const bf16x8*)(wb + 2 * 128 * 512 + 256);

    {   // rowset 0
      float f[8];
      *(float4*)&f[0] = *(const float4*)(xp0 + sl * 32);
      *(float4*)&f[4] = *(const float4*)(xp0 + sl * 32 + 4);
      SPLIT8(f, a0, a1, a2)
      g00 = __builtin_amdgcn_mfma_f32_16x16x32_bf16(a0, bg0, g00, 0, 0, 0);
      n00 = __builtin_amdgcn_mfma_f32_16x16x32_bf16(a0, bn0, n00, 0, 0, 0);
      g01 = __builtin_amdgcn_mfma_f32_16x16x32_bf16(a0, bg1, g01, 0, 0, 0);
      n01 = __builtin_amdgcn_mfma_f32_16x16x32_bf16(a0, bn1, n01, 0, 0, 0);
      g02 = __builtin_amdgcn_mfma_f32_16x16x32_bf16(a1, bg0, g02, 0, 0, 0);
      n02 = __builtin_amdgcn_mfma_f32_16x16x32_bf16(a1, bn0, n02, 0, 0, 0);
      g00 = __builtin_amdgcn_mfma_f32_16x16x32_bf16(a0, bg2, g00, 0, 0, 0);
      n00 = __builtin_amdgcn_mfma_f32_16x16x32_bf16(a0, bn2, n00, 0, 0, 0);
      g01 = __builtin_amdgcn_mfma_f32_16x16x32_bf16(a1, bg1, g01, 0, 0, 0);
      n01 = __builtin_amdgcn_mfma_f32_16x16x32_bf16(a1, bn1, n01, 0, 0, 0);
      g02 = __builtin_amdgcn_mfma_f32_16x16x32_bf16(a2, bg0, g02, 0, 0, 0);
      n02 = __builtin_amdgcn_mfma_f32_16x16x32_bf16(a2, bn0, n02, 0, 0, 0);
    }
    {   // rowset 1, same B frags
      float f[8];
      *(float4*)&f[0] = *(const float4*)(xp1 + sl * 32);
      *(float4*)&f[4] = *(const float4*)(xp1 + sl * 32 + 4);
      SPLIT8(f, a0, a1, a2)
      g10 = __builtin_amdgcn_mfma_f32_16x16x32_bf16(a0, bg0, g10, 0, 0, 0);
      n10 = __builtin_amdgcn_mfma_f32_16x16x32_bf16(a0, bn0, n10, 0, 0, 0);
      g11 = __builtin_amdgcn_mfma_f32_16x16x32_bf16(a0, bg1, g11, 0, 0, 0);
      n11 = __builtin_amdgcn_mfma_f32_16x16x32_bf16(a0, bn1, n11, 0, 0, 0);
      g12 = __builtin_amdgcn_mfma_f32_16x16x32_bf16(a1, bg0, g12, 0, 0, 0);
      n12 = __builtin_amdgcn_mfma_f32_16x16x32_bf16(a1, bn0, n12, 0, 0, 0);
      g10 = __builtin_amdgcn_mfma_f32_16x16x32_bf16(a0, bg2, g10, 0, 0, 0);
      n10 = __builtin_amdgcn_mfma_f32_16x16x32_bf16(a0, bn2, n10, 0, 0, 0);
      g11 = __builtin_amdgcn_mfma_f32_16x16x32_bf16(a1, bg1, g11, 0, 0, 0);
      n11 = __builtin_amdgcn_mfma_f32_16x16x32_bf16(a1, bn1, n11, 0, 0, 0);
      g12 = __builtin_amdgcn_mfma_f32_16x16x32_bf16(a2, bg0, g12, 0, 0, 0);
      n12 = __builtin_amdgcn_mfma_f32_16x16x32_bf16(a2, bn0, n12, 0, 0, 0);
    }
  }
#undef SPLIT8

  const f32x4 cg0 = g00 + g01 + g02;
  const f32x4 cn0 = n00 + n01 + n02;
  const f32x4 cg1 = g10 + g11 + g12;
  const f32x4 cn1 = n10 + n11 + n12;
#pragma unroll
  for (int j = 0; j < 4; ++j) {
    red[w][r * 32 + (c * 4 + j)]             = cg0[j];
    red[w][(16 + r) * 32 + (c * 4 + j)]      = cn0[j];
    red[w][r * 32 + 16 + (c * 4 + j)]        = cg1[j];
    red[w][(16 + r) * 32 + 16 + (c * 4 + j)] = cn1[j];
  }
  __syncthreads();
#pragma unroll
  for (int idx = t; idx < 1024; idx += 512) {
    float s = red[0][idx];
#pragma unroll
    for (int ww = 1; ww < 8; ++ww) s += red[ww][idx];
    red[0][idx] = s;
  }
  __syncthreads();

  if (t < 32) {
    const int row = rt * 32 + t;
    float dot[32];
#pragma unroll
    for (int e = 0; e < 32; ++e) dot[e] = red[0][e * 32 + t];
    float h[16];
#pragma unroll
    for (int e = 0; e < 16; ++e) h[e] = tanhf(dot[e]);
    float lg[16], nc[16], ln[16], lo[16];
#pragma unroll
    for (int j = 0; j < 16; ++j) {
      float s = 0.f;
#pragma unroll
      for (int e = 0; e < 16; ++e) s = fmaf(h[e], sg2[j * 16 + e], s);
      lg[j] = s;
      const float v = dot[16 + j];
      nc[j] = fmaxf(v, 0.f) + log1pf(expf(-fabsf(v))) + 0.01f;
      ln[j] = noise[(size_t)row * 16 + j] * nc[j];
      lo[j] = lg[j] + ln[j];
    }
    int i0 = 0; float m0 = lo[0];
#pragma unroll
    for (int j = 1; j < 16; ++j) if (lo[j] > m0) { m0 = lo[j]; i0 = j; }
    int i1 = -1; float m1 = -1e30f;
#pragma unroll
    for (int j = 0; j < 16; ++j) if (j != i0 && lo[j] > m1) { m1 = lo[j]; i1 = j; }
    float m2 = -1e30f;
#pragma unroll
    for (int j = 0; j < 16; ++j) if (j != i0 && j != i1 && lo[j] > m2) m2 = lo[j];

    const float e1 = expf(m1 - m0);
    const float s0 = 1.f / (1.f + e1);
    const float s1 = e1 / (1.f + e1);
    out[(size_t)row * 2]             = (float)i0;
    out[(size_t)row * 2 + 1]         = (float)i1;
    out[16384 + (size_t)row * 2]     = s0;
    out[16384 + (size_t)row * 2 + 1] = s1;

    float cacc[32];
#pragma unroll
    for (int j = 0; j < 16; ++j) {
      cacc[j] = (j == i0) ? s0 : ((j == i1) ? s1 : 0.f);
      const bool in = ln[j] > m2;
      const float thr = in ? m2 : m1;
      const float z = (lg[j] - thr) / nc[j];
      cacc[16 + j] = 0.5f * (1.f + erff(z * 0.70710678118654752f));
    }
#pragma unroll
    for (int off = 1; off < 16; off <<= 1) {
#pragma unroll
      for (int k = 0; k < 32; ++k) cacc[k] += __shfl_xor(cacc[k], off, 16);
    }
    const int g = rt * 2 + (t >> 4);
    const int rr = t & 15;
    float v0 = 0.f, v1 = 0.f;
#pragma unroll
    for (int k = 0; k < 16; ++k) if (rr == k) { v0 = cacc[k]; v1 = cacc[16 + k]; }
    part2[(size_t)g * 32 + rr]      = v0;
    part2[(size_t)g * 32 + 16 + rr] = v1;
  }

  grid.sync();   // part2 visible device-wide

  // ---------------- Phase C: loss (block 0; verbatim gate_loss_k body) ----------------
  if (bid == 0) {
    if (t < 256) {
      const int k = t & 31, s = t >> 5;
      float acc = 0.f;
#pragma unroll 8
      for (int i = 0; i < 64; ++i) acc += part2[(size_t)(s * 64 + i) * 32 + k];
      sred[s][k] = acc;
    }
    __syncthreads();
    if (t == 0) {
      float res = 0.f;
      for (int g = 0; g < 2; ++g) {
        float vals[16];
        float mu = 0.f;
        for (int j = 0; j < 16; ++j) {
          float s2 = 0.f;
          for (int ss = 0; ss < 8; ++ss) s2 += sred[ss][g * 16 + j];
          vals[j] = s2;
          mu += s2;
        }
        mu *= (1.f / 16.f);
        float var = 0.f;
        for (int j = 0; j < 16; ++j) { const float d = vals[j] - mu; var += d * d; }
        var *= (1.f / 15.f);
        res += var / (mu * mu + 1e-10f);
      }
      out[32768] = res * 0.01f;
    }
  }
}

extern "C" void kernel_launch(void* const* d_in, const int* in_sizes, int n_in,
                              void* d_out, int out_size, void* d_ws, size_t ws_size,
                              hipStream_t stream) {
  const float* x     = (const float*)d_in[0];
  const float* gw1   = (const float*)d_in[1];
  const float* gw2   = (const float*)d_in[2];
  const float* nw    = (const float*)d_in[3];
  const float* noise = (const float*)d_in[4];
  float* out   = (float*)d_out;
  u32*   wfrag = (u32*)d_ws;                                   // 768 KB, fully written
  float* part2 = (float*)((char*)d_ws + (size_t)768 * 1024);   // 64 KB, fully written

  void* args[] = { (void*)&x, (void*)&wfrag, (void*)&noise, (void*)&gw2,
                   (void*)&out, (void*)&part2, (void*)&gw1, (void*)&nw };
  hipLaunchCooperativeKernel((const void*)gate_fused, dim3(256), dim3(512),
                             args, 0, stream);
}

// Round 16
// 61.735 us; speedup vs baseline: 1.7564x; 1.7564x over previous
//
#include <hip/hip_runtime.h>
#include <math.h>

#define TT 8192
#define DD 4096

typedef float  f32x4  __attribute__((ext_vector_type(4)));
typedef short  bf16x8 __attribute__((ext_vector_type(8)));
typedef unsigned int u32;

// ---------------- Kernel P: split weights into 3 bf16 planes, frag-ordered ----------------
// wfrag word layout: ((p*128 + s)*2 + h)*256 + l*4  (uint4 per lane = 8 bf16)
// k = s*32 + (l>>4)*8 + i ; expert e = h*16 + (l&15).  Also zeroes the done-counter.
__global__ __launch_bounds__(128)
void split_w(const float* __restrict__ gw1, const float* __restrict__ nw,
             u32* __restrict__ wfrag, u32* __restrict__ cnt) {
  const int s = blockIdx.x;          // 128 k-steps
  const int t = threadIdx.x;
  if (s == 0 && t == 0) *cnt = 0;    // reset last-block counter (stream-ordered)
  const int h = t >> 6, l = t & 63;
  const int e = h * 16 + (l & 15);
  const float* src = ((e < 16) ? (gw1 + (size_t)e * DD) : (nw + (size_t)(e - 16) * DD))
                     + s * 32 + ((l >> 4) << 3);
  float f[8];
  *(float4*)&f[0] = *(const float4*)src;
  *(float4*)&f[4] = *(const float4*)(src + 4);
  u32 u0[8], u1[8], u2[8];
#pragma unroll
  for (int i = 0; i < 8; ++i) {
    u0[i] = __float_as_uint(f[i]);
    const float r1 = f[i] - __uint_as_float(u0[i] & 0xFFFF0000u);
    u1[i] = __float_as_uint(r1);
    const float r2 = r1 - __uint_as_float(u1[i] & 0xFFFF0000u);
    u2[i] = __float_as_uint(r2);
  }
  const size_t base = ((size_t)s * 2 + h) * 256 + l * 4;
#define PK(U) make_uint4((U[0]>>16)|(U[1]&0xFFFF0000u), (U[2]>>16)|(U[3]&0xFFFF0000u), \
                         (U[4]>>16)|(U[5]&0xFFFF0000u), (U[6]>>16)|(U[7]&0xFFFF0000u))
  *(uint4*)(wfrag + base)                 = PK(u0);
  *(uint4*)(wfrag + base + 128 * 512)     = PK(u1);   // plane stride = 128*2*256 words
  *(uint4*)(wfrag + base + 2 * 128 * 512) = PK(u2);
#undef PK
}

// ---------------- Kernel M: R11 (best-known) + last-block loss fusion ----------------
// 256 blocks x 8 waves; block = 32 rows, wave w = k-slice w*512 over all 32 rows.
// GEMM body VERBATIM from R11 (59.5us, passed). After part2 store: release fence +
// atomicAdd; the 256th block acquires and runs the loss reduction (gate_loss_k body
// verbatim). No spinning -> no deadlock; device-scope atomics/fences for cross-XCD.
__global__ __launch_bounds__(512, 4)
void gate_mega(const float* __restrict__ x, const u32* __restrict__ wfrag,
               const float* __restrict__ noise, const float* __restrict__ gw2,
               float* __restrict__ out, float* __restrict__ part2,
               u32* __restrict__ cnt) {
  __shared__ float red[8][1024];     // 32 KB: [slice][e*32 + row_in_block]
  __shared__ float sg2[256];
  __shared__ float sredl[8][32];
  __shared__ int lastf;
  const int t = threadIdx.x;
  const int w = t >> 6, l = t & 63;
  const int rt = blockIdx.x;         // 32-row tile 0..255
  if (t < 256) sg2[t] = gw2[t];

  const int r = l & 15, c = l >> 4;
  const float* xp0 = x + (size_t)(rt * 32 + r) * DD + w * 512 + (c << 3);
  const float* xp1 = xp0 + (size_t)16 * DD;
  const u32* wfl = wfrag + (size_t)l * 4 + (size_t)(w * 16) * 512;

  f32x4 g00 = {0,0,0,0}, g01 = g00, g02 = g00, n00 = g00, n01 = g00, n02 = g00;
  f32x4 g10 = g00, g11 = g00, g12 = g00, n10 = g00, n11 = g00, n12 = g00;

#define SPLIT8(FP, A0, A1, A2) \
  u32 pk_[12] __attribute__((aligned(16))); \
  { _Pragma("unroll") for (int p = 0; p < 4; ++p) { \
      const float fa = FP[2*p], fb = FP[2*p+1]; \
      const u32  a  = __float_as_uint(fa); \
      const float ra1 = fa - __uint_as_float(a & 0xFFFF0000u); \
      const u32  a1 = __float_as_uint(ra1); \
      const float ra2 = ra1 - __uint_as_float(a1 & 0xFFFF0000u); \
      const u32  a2 = __float_as_uint(ra2); \
      const u32  b  = __float_as_uint(fb); \
      const float rb1 = fb - __uint_as_float(b & 0xFFFF0000u); \
      const u32  b1 = __float_as_uint(rb1); \
      const float rb2 = rb1 - __uint_as_float(b1 & 0xFFFF0000u); \
      const u32  b2 = __float_as_uint(rb2); \
      pk_[p]     = (a  >> 16) | (b  & 0xFFFF0000u); \
      pk_[4 + p] = (a1 >> 16) | (b1 & 0xFFFF0000u); \
      pk_[8 + p] = (a2 >> 16) | (b2 & 0xFFFF0000u); } } \
  const bf16x8 A0 = *(const bf16x8*)&pk_[0]; \
  const bf16x8 A1 = *(const bf16x8*)&pk_[4]; \
  const bf16x8 A2 = *(const bf16x8*)&pk_[8];

#pragma unroll 2
  for (int sl = 0; sl < 16; ++sl) {
    const u32* wb = wfl + (size_t)sl * 512;
    const bf16x8 bg0 = *(const bf16x8*)(wb);
    const bf16x8 bn0 = *(const bf16x8*)(wb + 256);
    const bf16x8 bg1 = *(const bf16x8*)(wb + 128 * 512);
    const bf16x8 bn1 = *(const bf16x8*)(wb + 128 * 512 + 256);
    const bf16x8 bg2 = *(const bf16x8*)(wb + 2 * 128 * 512);
    const bf16x8 bn2 = *(const bf16x8*)(wb + 2 * 128 * 512 + 256);

    {   // rowset 0 (rows rt*32 + r)
      float f[8];
      *(float4*)&f[0] = *(const float4*)(xp0 + sl * 32);
      *(float4*)&f[4] = *(const float4*)(xp0 + sl * 32 + 4);
      SPLIT8(f, a0, a1, a2)
      g00 = __builtin_amdgcn_mfma_f32_16x16x32_bf16(a0, bg0, g00, 0, 0, 0);
      n00 = __builtin_amdgcn_mfma_f32_16x16x32_bf16(a0, bn0, n00, 0, 0, 0);
      g01 = __builtin_amdgcn_mfma_f32_16x16x32_bf16(a0, bg1, g01, 0, 0, 0);
      n01 = __builtin_amdgcn_mfma_f32_16x16x32_bf16(a0, bn1, n01, 0, 0, 0);
      g02 = __builtin_amdgcn_mfma_f32_16x16x32_bf16(a1, bg0, g02, 0, 0, 0);
      n02 = __builtin_amdgcn_mfma_f32_16x16x32_bf16(a1, bn0, n02, 0, 0, 0);
      g00 = __builtin_amdgcn_mfma_f32_16x16x32_bf16(a0, bg2, g00, 0, 0, 0);
      n00 = __builtin_amdgcn_mfma_f32_16x16x32_bf16(a0, bn2, n00, 0, 0, 0);
      g01 = __builtin_amdgcn_mfma_f32_16x16x32_bf16(a1, bg1, g01, 0, 0, 0);
      n01 = __builtin_amdgcn_mfma_f32_16x16x32_bf16(a1, bn1, n01, 0, 0, 0);
      g02 = __builtin_amdgcn_mfma_f32_16x16x32_bf16(a2, bg0, g02, 0, 0, 0);
      n02 = __builtin_amdgcn_mfma_f32_16x16x32_bf16(a2, bn0, n02, 0, 0, 0);
    }
    {   // rowset 1 (rows rt*32 + 16 + r), same B frags
      float f[8];
      *(float4*)&f[0] = *(const float4*)(xp1 + sl * 32);
      *(float4*)&f[4] = *(const float4*)(xp1 + sl * 32 + 4);
      SPLIT8(f, a0, a1, a2)
      g10 = __builtin_amdgcn_mfma_f32_16x16x32_bf16(a0, bg0, g10, 0, 0, 0);
      n10 = __builtin_amdgcn_mfma_f32_16x16x32_bf16(a0, bn0, n10, 0, 0, 0);
      g11 = __builtin_amdgcn_mfma_f32_16x16x32_bf16(a0, bg1, g11, 0, 0, 0);
      n11 = __builtin_amdgcn_mfma_f32_16x16x32_bf16(a0, bn1, n11, 0, 0, 0);
      g12 = __builtin_amdgcn_mfma_f32_16x16x32_bf16(a1, bg0, g12, 0, 0, 0);
      n12 = __builtin_amdgcn_mfma_f32_16x16x32_bf16(a1, bn0, n12, 0, 0, 0);
      g10 = __builtin_amdgcn_mfma_f32_16x16x32_bf16(a0, bg2, g10, 0, 0, 0);
      n10 = __builtin_amdgcn_mfma_f32_16x16x32_bf16(a0, bn2, n10, 0, 0, 0);
      g11 = __builtin_amdgcn_mfma_f32_16x16x32_bf16(a1, bg1, g11, 0, 0, 0);
      n11 = __builtin_amdgcn_mfma_f32_16x16x32_bf16(a1, bn1, n11, 0, 0, 0);
      g12 = __builtin_amdgcn_mfma_f32_16x16x32_bf16(a2, bg0, g12, 0, 0, 0);
      n12 = __builtin_amdgcn_mfma_f32_16x16x32_bf16(a2, bn0, n12, 0, 0, 0);
    }
  }
#undef SPLIT8

  const f32x4 cg0 = g00 + g01 + g02;
  const f32x4 cn0 = n00 + n01 + n02;
  const f32x4 cg1 = g10 + g11 + g12;
  const f32x4 cn1 = n10 + n11 + n12;
  // C/D: col(lane&15)=expert, row=(lane>>4)*4+reg [m89]. red[slice][e*32 + row_in_block].
#pragma unroll
  for (int j = 0; j < 4; ++j) {
    red[w][r * 32 + (c * 4 + j)]             = cg0[j];
    red[w][(16 + r) * 32 + (c * 4 + j)]      = cn0[j];
    red[w][r * 32 + 16 + (c * 4 + j)]        = cg1[j];
    red[w][(16 + r) * 32 + 16 + (c * 4 + j)] = cn1[j];
  }
  __syncthreads();
  // reduce across the 8 k-slices, ascending order; each column owned by one thread.
#pragma unroll
  for (int idx = t; idx < 1024; idx += 512) {
    float s = red[0][idx];
#pragma unroll
    for (int ww = 1; ww < 8; ++ww) s += red[ww][idx];
    red[0][idx] = s;
  }
  __syncthreads();

  if (t < 32) {
    const int row = rt * 32 + t;
    float dot[32];
#pragma unroll
    for (int e = 0; e < 32; ++e) dot[e] = red[0][e * 32 + t];
    float h[16];
#pragma unroll
    for (int e = 0; e < 16; ++e) h[e] = tanhf(dot[e]);
    float lg[16], nc[16], ln[16], lo[16];
#pragma unroll
    for (int j = 0; j < 16; ++j) {
      float s = 0.f;
#pragma unroll
      for (int e = 0; e < 16; ++e) s = fmaf(h[e], sg2[j * 16 + e], s);
      lg[j] = s;
      const float v = dot[16 + j];
      nc[j] = fmaxf(v, 0.f) + log1pf(expf(-fabsf(v))) + 0.01f;
      ln[j] = noise[(size_t)row * 16 + j] * nc[j];
      lo[j] = lg[j] + ln[j];
    }
    int i0 = 0; float m0 = lo[0];
#pragma unroll
    for (int j = 1; j < 16; ++j) if (lo[j] > m0) { m0 = lo[j]; i0 = j; }
    int i1 = -1; float m1 = -1e30f;
#pragma unroll
    for (int j = 0; j < 16; ++j) if (j != i0 && lo[j] > m1) { m1 = lo[j]; i1 = j; }
    float m2 = -1e30f;
#pragma unroll
    for (int j = 0; j < 16; ++j) if (j != i0 && j != i1 && lo[j] > m2) m2 = lo[j];

    const float e1 = expf(m1 - m0);
    const float s0 = 1.f / (1.f + e1);
    const float s1 = e1 / (1.f + e1);
    out[(size_t)row * 2]             = (float)i0;
    out[(size_t)row * 2 + 1]         = (float)i1;
    out[16384 + (size_t)row * 2]     = s0;
    out[16384 + (size_t)row * 2 + 1] = s1;

    float cacc[32];
#pragma unroll
    for (int j = 0; j < 16; ++j) {
      cacc[j] = (j == i0) ? s0 : ((j == i1) ? s1 : 0.f);
      const bool in = ln[j] > m2;
      const float thr = in ? m2 : m1;
      const float z = (lg[j] - thr) / nc[j];
      cacc[16 + j] = 0.5f * (1.f + erff(z * 0.70710678118654752f));
    }
    // reduce the 32 loss partials within each 16-row group (xor<16 stays in-group)
#pragma unroll
    for (int off = 1; off < 16; off <<= 1) {
#pragma unroll
      for (int k = 0; k < 32; ++k) cacc[k] += __shfl_xor(cacc[k], off, 16);
    }
    // group g = rt*2 + (t>>4): exact part2 layout/order of prior rounds (512 groups)
    const int g = rt * 2 + (t >> 4);
    const int rr = t & 15;
    float v0 = 0.f, v1 = 0.f;
#pragma unroll
    for (int k = 0; k < 16; ++k) if (rr == k) { v0 = cacc[k]; v1 = cacc[16 + k]; }
    part2[(size_t)g * 32 + rr]      = v0;
    part2[(size_t)g * 32 + 16 + rr] = v1;
  }

  // ---- last-block-done: release my part2 stores, count blocks, last runs the loss ----
  __syncthreads();                       // block's part2 stores complete
  if (t == 0) {
    __threadfence();                     // device-scope release (chained via barrier)
    lastf = (atomicAdd(cnt, 1u) == 255u);
  }
  __syncthreads();
  if (lastf) {
    __threadfence();                     // device-scope acquire
    if (t < 256) {
      const int k = t & 31, s = t >> 5;
      float acc = 0.f;
#pragma unroll 8
      for (int i = 0; i < 64; ++i) acc += part2[(size_t)(s * 64 + i) * 32 + k];
      sredl[s][k] = acc;
    }
    __syncthreads();
    if (t == 0) {
      float res = 0.f;
      for (int g = 0; g < 2; ++g) {
        float vals[16];
        float mu = 0.f;
        for (int j = 0; j < 16; ++j) {
          float s2 = 0.f;
          for (int ss = 0; ss < 8; ++ss) s2 += sredl[ss][g * 16 + j];
          vals[j] = s2;
          mu += s2;
        }
        mu *= (1.f / 16.f);
        float var = 0.f;
        for (int j = 0; j < 16; ++j) { const float d = vals[j] - mu; var += d * d; }
        var *= (1.f / 15.f);
        res += var / (mu * mu + 1e-10f);
      }
      out[32768] = res * 0.01f;
    }
  }
}

extern "C" void kernel_launch(void* const* d_in, const int* in_sizes, int n_in,
                              void* d_out, int out_size, void* d_ws, size_t ws_size,
                              hipStream_t stream) {
  const float* x     = (const float*)d_in[0];
  const float* gw1   = (const float*)d_in[1];
  const float* gw2   = (const float*)d_in[2];
  const float* nw    = (const float*)d_in[3];
  const float* noise = (const float*)d_in[4];
  float* out   = (float*)d_out;
  u32*   wfrag = (u32*)d_ws;                                        // 768 KB
  float* part2 = (float*)((char*)d_ws + (size_t)768 * 1024);        // 64 KB
  u32*   cnt   = (u32*)((char*)d_ws + (size_t)768 * 1024 + 65536);  // 4 B
  split_w<<<128, 128, 0, stream>>>(gw1, nw, wfrag, cnt);
  gate_mega<<<256, 512, 0, stream>>>(x, wfrag, noise, gw2, out, part2, cnt);
}

// Round 17
// 60.933 us; speedup vs baseline: 1.7795x; 1.0132x over previous
//
#include <hip/hip_runtime.h>
#include <math.h>

#define TT 8192
#define DD 4096

typedef float  f32x4  __attribute__((ext_vector_type(4)));
typedef short  bf16x8 __attribute__((ext_vector_type(8)));
typedef unsigned int u32;

// ---------------- Kernel P: split weights into 3 bf16 planes, frag-ordered ----------------
// wfrag word layout: ((p*128 + s)*2 + h)*256 + l*4  (uint4 per lane = 8 bf16)
// k = s*32 + (l>>4)*8 + i ; expert e = h*16 + (l&15).
__global__ __launch_bounds__(128)
void split_w(const float* __restrict__ gw1, const float* __restrict__ nw,
             u32* __restrict__ wfrag) {
  const int s = blockIdx.x;          // 128 k-steps
  const int t = threadIdx.x;
  const int h = t >> 6, l = t & 63;
  const int e = h * 16 + (l & 15);
  const float* src = ((e < 16) ? (gw1 + (size_t)e * DD) : (nw + (size_t)(e - 16) * DD))
                     + s * 32 + ((l >> 4) << 3);
  float f[8];
  *(float4*)&f[0] = *(const float4*)src;
  *(float4*)&f[4] = *(const float4*)(src + 4);
  u32 u0[8], u1[8], u2[8];
#pragma unroll
  for (int i = 0; i < 8; ++i) {
    u0[i] = __float_as_uint(f[i]);
    const float r1 = f[i] - __uint_as_float(u0[i] & 0xFFFF0000u);
    u1[i] = __float_as_uint(r1);
    const float r2 = r1 - __uint_as_float(u1[i] & 0xFFFF0000u);
    u2[i] = __float_as_uint(r2);
  }
  const size_t base = ((size_t)s * 2 + h) * 256 + l * 4;
#define PK(U) make_uint4((U[0]>>16)|(U[1]&0xFFFF0000u), (U[2]>>16)|(U[3]&0xFFFF0000u), \
                         (U[4]>>16)|(U[5]&0xFFFF0000u), (U[6]>>16)|(U[7]&0xFFFF0000u))
  *(uint4*)(wfrag + base)                 = PK(u0);
  *(uint4*)(wfrag + base + 128 * 512)     = PK(u1);   // plane stride = 128*2*256 words
  *(uint4*)(wfrag + base + 2 * 128 * 512) = PK(u2);
#undef PK
}

// ---------------- Kernel M: 32-rows-per-wave register blocking (B reuse x2) ----------------
// 256 blocks x 8 waves; block = 32 rows, wave w = k-slice w*512 over ALL 32 rows.
// Two 16-row A-fragments share the same 6 B-frags per iteration: 24 MFMA / 10 VMEM.
// Best-known configuration (R11, 59.5us). Plain loads, no pinning, no in-loop barriers.
__global__ __launch_bounds__(512, 4)
void gate_mega(const float* __restrict__ x, const u32* __restrict__ wfrag,
               const float* __restrict__ noise, const float* __restrict__ gw2,
               float* __restrict__ out, float* __restrict__ part2) {
  __shared__ float red[8][1024];     // 32 KB: [slice][e*32 + row_in_block]
  __shared__ float sg2[256];
  const int t = threadIdx.x;
  const int w = t >> 6, l = t & 63;
  const int rt = blockIdx.x;         // 32-row tile 0..255
  if (t < 256) sg2[t] = gw2[t];

  const int r = l & 15, c = l >> 4;
  const float* xp0 = x + (size_t)(rt * 32 + r) * DD + w * 512 + (c << 3);
  const float* xp1 = xp0 + (size_t)16 * DD;
  const u32* wfl = wfrag + (size_t)l * 4 + (size_t)(w * 16) * 512;

  f32x4 g00 = {0,0,0,0}, g01 = g00, g02 = g00, n00 = g00, n01 = g00, n02 = g00;
  f32x4 g10 = g00, g11 = g00, g12 = g00, n10 = g00, n11 = g00, n12 = g00;

#define SPLIT8(FP, A0, A1, A2) \
  u32 pk_[12] __attribute__((aligned(16))); \
  { _Pragma("unroll") for (int p = 0; p < 4; ++p) { \
      const float fa = FP[2*p], fb = FP[2*p+1]; \
      const u32  a  = __float_as_uint(fa); \
      const float ra1 = fa - __uint_as_float(a & 0xFFFF0000u); \
      const u32  a1 = __float_as_uint(ra1); \
      const float ra2 = ra1 - __uint_as_float(a1 & 0xFFFF0000u); \
      const u32  a2 = __float_as_uint(ra2); \
      const u32  b  = __float_as_uint(fb); \
      const float rb1 = fb - __uint_as_float(b & 0xFFFF0000u); \
      const u32  b1 = __float_as_uint(rb1); \
      const float rb2 = rb1 - __uint_as_float(b1 & 0xFFFF0000u); \
      const u32  b2 = __float_as_uint(rb2); \
      pk_[p]     = (a  >> 16) | (b  & 0xFFFF0000u); \
      pk_[4 + p] = (a1 >> 16) | (b1 & 0xFFFF0000u); \
      pk_[8 + p] = (a2 >> 16) | (b2 & 0xFFFF0000u); } } \
  const bf16x8 A0 = *(const bf16x8*)&pk_[0]; \
  const bf16x8 A1 = *(const bf16x8*)&pk_[4]; \
  const bf16x8 A2 = *(const bf16x8*)&pk_[8];

#pragma unroll 2
  for (int sl = 0; sl < 16; ++sl) {
    const u32* wb = wfl + (size_t)sl * 512;
    const bf16x8 bg0 = *(const bf16x8*)(wb);
    const bf16x8 bn0 = *(const bf16x8*)(wb + 256);
    const bf16x8 bg1 = *(const bf16x8*)(wb + 128 * 512);
    const bf16x8 bn1 = *(const bf16x8*)(wb + 128 * 512 + 256);
    const bf16x8 bg2 = *(const bf16x8*)(wb + 2 * 128 * 512);
    const bf16x8 bn2 = *(const bf16x8*)(wb + 2 * 128 * 512 + 256);

    {   // rowset 0 (rows rt*32 + r)
      float f[8];
      *(float4*)&f[0] = *(const float4*)(xp0 + sl * 32);
      *(float4*)&f[4] = *(const float4*)(xp0 + sl * 32 + 4);
      SPLIT8(f, a0, a1, a2)
      g00 = __builtin_amdgcn_mfma_f32_16x16x32_bf16(a0, bg0, g00, 0, 0, 0);
      n00 = __builtin_amdgcn_mfma_f32_16x16x32_bf16(a0, bn0, n00, 0, 0, 0);
      g01 = __builtin_amdgcn_mfma_f32_16x16x32_bf16(a0, bg1, g01, 0, 0, 0);
      n01 = __builtin_amdgcn_mfma_f32_16x16x32_bf16(a0, bn1, n01, 0, 0, 0);
      g02 = __builtin_amdgcn_mfma_f32_16x16x32_bf16(a1, bg0, g02, 0, 0, 0);
      n02 = __builtin_amdgcn_mfma_f32_16x16x32_bf16(a1, bn0, n02, 0, 0, 0);
      g00 = __builtin_amdgcn_mfma_f32_16x16x32_bf16(a0, bg2, g00, 0, 0, 0);
      n00 = __builtin_amdgcn_mfma_f32_16x16x32_bf16(a0, bn2, n00, 0, 0, 0);
      g01 = __builtin_amdgcn_mfma_f32_16x16x32_bf16(a1, bg1, g01, 0, 0, 0);
      n01 = __builtin_amdgcn_mfma_f32_16x16x32_bf16(a1, bn1, n01, 0, 0, 0);
      g02 = __builtin_amdgcn_mfma_f32_16x16x32_bf16(a2, bg0, g02, 0, 0, 0);
      n02 = __builtin_amdgcn_mfma_f32_16x16x32_bf16(a2, bn0, n02, 0, 0, 0);
    }
    {   // rowset 1 (rows rt*32 + 16 + r), same B frags
      float f[8];
      *(float4*)&f[0] = *(const float4*)(xp1 + sl * 32);
      *(float4*)&f[4] = *(const float4*)(xp1 + sl * 32 + 4);
      SPLIT8(f, a0, a1, a2)
      g10 = __builtin_amdgcn_mfma_f32_16x16x32_bf16(a0, bg0, g10, 0, 0, 0);
      n10 = __builtin_amdgcn_mfma_f32_16x16x32_bf16(a0, bn0, n10, 0, 0, 0);
      g11 = __builtin_amdgcn_mfma_f32_16x16x32_bf16(a0, bg1, g11, 0, 0, 0);
      n11 = __builtin_amdgcn_mfma_f32_16x16x32_bf16(a0, bn1, n11, 0, 0, 0);
      g12 = __builtin_amdgcn_mfma_f32_16x16x32_bf16(a1, bg0, g12, 0, 0, 0);
      n12 = __builtin_amdgcn_mfma_f32_16x16x32_bf16(a1, bn0, n12, 0, 0, 0);
      g10 = __builtin_amdgcn_mfma_f32_16x16x32_bf16(a0, bg2, g10, 0, 0, 0);
      n10 = __builtin_amdgcn_mfma_f32_16x16x32_bf16(a0, bn2, n10, 0, 0, 0);
      g11 = __builtin_amdgcn_mfma_f32_16x16x32_bf16(a1, bg1, g11, 0, 0, 0);
      n11 = __builtin_amdgcn_mfma_f32_16x16x32_bf16(a1, bn1, n11, 0, 0, 0);
      g12 = __builtin_amdgcn_mfma_f32_16x16x32_bf16(a2, bg0, g12, 0, 0, 0);
      n12 = __builtin_amdgcn_mfma_f32_16x16x32_bf16(a2, bn0, n12, 0, 0, 0);
    }
  }
#undef SPLIT8

  const f32x4 cg0 = g00 + g01 + g02;
  const f32x4 cn0 = n00 + n01 + n02;
  const f32x4 cg1 = g10 + g11 + g12;
  const f32x4 cn1 = n10 + n11 + n12;
  // C/D: col(lane&15)=expert, row=(lane>>4)*4+reg [m89]. red[slice][e*32 + row_in_block].
#pragma unroll
  for (int j = 0; j < 4; ++j) {
    red[w][r * 32 + (c * 4 + j)]             = cg0[j];
    red[w][(16 + r) * 32 + (c * 4 + j)]      = cn0[j];
    red[w][r * 32 + 16 + (c * 4 + j)]        = cg1[j];
    red[w][(16 + r) * 32 + 16 + (c * 4 + j)] = cn1[j];
  }
  __syncthreads();
  // reduce across the 8 k-slices, ascending order; each column owned by one thread.
#pragma unroll
  for (int idx = t; idx < 1024; idx += 512) {
    float s = red[0][idx];
#pragma unroll
    for (int ww = 1; ww < 8; ++ww) s += red[ww][idx];
    red[0][idx] = s;
  }
  __syncthreads();

  if (t < 32) {
    const int row = rt * 32 + t;
    float dot[32];
#pragma unroll
    for (int e = 0; e < 32; ++e) dot[e] = red[0][e * 32 + t];
    float h[16];
#pragma unroll
    for (int e = 0; e < 16; ++e) h[e] = tanhf(dot[e]);
    float lg[16], nc[16], ln[16], lo[16];
#pragma unroll
    for (int j = 0; j < 16; ++j) {
      float s = 0.f;
#pragma unroll
      for (int e = 0; e < 16; ++e) s = fmaf(h[e], sg2[j * 16 + e], s);
      lg[j] = s;
      const float v = dot[16 + j];
      nc[j] = fmaxf(v, 0.f) + log1pf(expf(-fabsf(v))) + 0.01f;
      ln[j] = noise[(size_t)row * 16 + j] * nc[j];
      lo[j] = lg[j] + ln[j];
    }
    int i0 = 0; float m0 = lo[0];
#pragma unroll
    for (int j = 1; j < 16; ++j) if (lo[j] > m0) { m0 = lo[j]; i0 = j; }
    int i1 = -1; float m1 = -1e30f;
#pragma unroll
    for (int j = 0; j < 16; ++j) if (j != i0 && lo[j] > m1) { m1 = lo[j]; i1 = j; }
    float m2 = -1e30f;
#pragma unroll
    for (int j = 0; j < 16; ++j) if (j != i0 && j != i1 && lo[j] > m2) m2 = lo[j];

    const float e1 = expf(m1 - m0);
    const float s0 = 1.f / (1.f + e1);
    const float s1 = e1 / (1.f + e1);
    out[(size_t)row * 2]             = (float)i0;
    out[(size_t)row * 2 + 1]         = (float)i1;
    out[16384 + (size_t)row * 2]     = s0;
    out[16384 + (size_t)row * 2 + 1] = s1;

    float cacc[32];
#pragma unroll
    for (int j = 0; j < 16; ++j) {
      cacc[j] = (j == i0) ? s0 : ((j == i1) ? s1 : 0.f);
      const bool in = ln[j] > m2;
      const float thr = in ? m2 : m1;
      const float z = (lg[j] - thr) / nc[j];
      cacc[16 + j] = 0.5f * (1.f + erff(z * 0.70710678118654752f));
    }
    // reduce the 32 loss partials within each 16-row group (xor<16 stays in-group)
#pragma unroll
    for (int off = 1; off < 16; off <<= 1) {
#pragma unroll
      for (int k = 0; k < 32; ++k) cacc[k] += __shfl_xor(cacc[k], off, 16);
    }
    // group g = rt*2 + (t>>4): exact part2 layout/order of prior rounds (512 groups)
    const int g = rt * 2 + (t >> 4);
    const int rr = t & 15;
    float v0 = 0.f, v1 = 0.f;
#pragma unroll
    for (int k = 0; k < 16; ++k) if (rr == k) { v0 = cacc[k]; v1 = cacc[16 + k]; }
    part2[(size_t)g * 32 + rr]      = v0;
    part2[(size_t)g * 32 + 16 + rr] = v1;
  }
}

// ---------------- Kernel C: reduce per-block partials -> cv^2 loss ----------------
__global__ __launch_bounds__(256)
void gate_loss_k(const float* __restrict__ part2, float* __restrict__ out) {
  __shared__ float sred[8][32];
  const int t = threadIdx.x;        // 256
  const int k = t & 31, s = t >> 5; // expert, group-slice (8 slices of 64 groups)
  float acc = 0.f;
#pragma unroll 8
  for (int i = 0; i < 64; ++i) acc += part2[(size_t)(s * 64 + i) * 32 + k];
  sred[s][k] = acc;
  __syncthreads();
  if (t == 0) {
    float res = 0.f;
    for (int g = 0; g < 2; ++g) {
      float vals[16];
      float mu = 0.f;
      for (int j = 0; j < 16; ++j) {
        float s2 = 0.f;
        for (int ss = 0; ss < 8; ++ss) s2 += sred[ss][g * 16 + j];
        vals[j] = s2;
        mu += s2;
      }
      mu *= (1.f / 16.f);
      float var = 0.f;
      for (int j = 0; j < 16; ++j) { const float d = vals[j] - mu; var += d * d; }
      var *= (1.f / 15.f);
      res += var / (mu * mu + 1e-10f);
    }
    out[32768] = res * 0.01f;
  }
}

extern "C" void kernel_launch(void* const* d_in, const int* in_sizes, int n_in,
                              void* d_out, int out_size, void* d_ws, size_t ws_size,
                              hipStream_t stream) {
  const float* x     = (const float*)d_in[0];
  const float* gw1   = (const float*)d_in[1];
  const float* gw2   = (const float*)d_in[2];
  const float* nw    = (const float*)d_in[3];
  const float* noise = (const float*)d_in[4];
  float* out   = (float*)d_out;
  u32*   wfrag = (u32*)d_ws;                                   // 768 KB, fully written
  float* part2 = (float*)((char*)d_ws + (size_t)768 * 1024);   // 64 KB, fully written
  split_w<<<128, 128, 0, stream>>>(gw1, nw, wfrag);
  gate_mega<<<256, 512, 0, stream>>>(x, wfrag, noise, gw2, out, part2);
  gate_loss_k<<<1, 256, 0, stream>>>(part2, out);
}